// Round 3
// baseline (280.784 us; speedup 1.0000x reference)
//
#include <hip/hip_runtime.h>

#define SEQ 512
#define BATCH 1024
#define NT 64
#define BT (BATCH * NT)        // stride between timesteps in emissions
#define NUMER_BLOCKS 512
#define LN2F 0.69314718055994531f

// Fused kernel: blocks [0, BATCH) run the forward-algorithm denominator (one
// wave per chain, linear domain, power-of-2 rescaling; no exp/log on the
// critical path). Blocks [BATCH, ...) accumulate the tag-path numerator.
// NOTE: no asm memory clobbers anywhere in the hot loop — LDS write->read
// ordering is guaranteed by may-alias analysis + in-order DS pipe per wave.
__global__ __launch_bounds__(64, 1) void crf_fused(
    const float* __restrict__ em, const int* __restrict__ tags,
    const int* __restrict__ lens, const float* __restrict__ st,
    const float* __restrict__ en, const float* __restrict__ tr,
    float* __restrict__ out)
{
    __shared__ __align__(16) float p_sh[NT];
    const int lane = threadIdx.x;   // block = 1 wave

    if (blockIdx.x < BATCH) {
        // ---------------- denominator: one wave per batch chain ----------------
        const int b = blockIdx.x;
        const int L = lens[b];

        // Register-resident E column: e[i] = exp(trans[i][lane])
        float e[NT];
        #pragma unroll
        for (int i = 0; i < NT; ++i) e[i] = __expf(tr[i * NT + lane]);

        const float* emb = em + (size_t)b * NT + lane;

        // init: x0_j = st_j + em0_j ; q_j = exp(x0_j - x0_0)
        float x0 = st[lane] + emb[0];
        float xs = __uint_as_float(__builtin_amdgcn_readfirstlane(__float_as_uint(x0)));
        float q = __expf(x0 - xs);
        int ksum = 0;

        // 2-deep emission prefetch, branchless clamped indices
        int i1 = (L > 1) ? 1 : 0;
        int i2 = (L > 2) ? 2 : i1;
        float em_n0 = emb[(size_t)i1 * BT];
        float em_n1 = emb[(size_t)i2 * BT];

        for (int s = 1; s < L; ++s) {
            float mult = __expf(em_n0);            // exp of this step's emission
            em_n0 = em_n1;
            int snx = s + 2;
            snx = (snx > L - 1) ? (L - 1) : snx;
            em_n1 = emb[(size_t)snx * BT];

            p_sh[lane] = q;                        // broadcast my state prob

            float d0 = 0.f, d1 = 0.f, d2 = 0.f, d3 = 0.f;
            float d4 = 0.f, d5 = 0.f, d6 = 0.f, d7 = 0.f;
            const float4* pv = reinterpret_cast<const float4*>(p_sh);
            #pragma unroll
            for (int i = 0; i < NT; i += 8) {
                float4 a = pv[i / 4];              // same-addr broadcast ds_read_b128
                float4 c = pv[i / 4 + 1];
                d0 = fmaf(a.x, e[i + 0], d0);
                d1 = fmaf(a.y, e[i + 1], d1);
                d2 = fmaf(a.z, e[i + 2], d2);
                d3 = fmaf(a.w, e[i + 3], d3);
                d4 = fmaf(c.x, e[i + 4], d4);
                d5 = fmaf(c.y, e[i + 5], d5);
                d6 = fmaf(c.z, e[i + 6], d6);
                d7 = fmaf(c.w, e[i + 7], d7);
            }
            float dot = ((d0 + d1) + (d2 + d3)) + ((d4 + d5) + (d6 + d7));

            // rescale by 2^-k, k = exponent of lane-0's dot (pre-emission, so the
            // SALU extraction overlaps the mult multiply). dot > 0 always.
            unsigned b0 = __builtin_amdgcn_readfirstlane(__float_as_uint(dot));
            int k = (int)(b0 >> 23) - 127;
            ksum += k;
            float scale = __uint_as_float((unsigned)(127 - k) << 23);  // 2^-k
            q = dot * mult * scale;
        }

        // denom_b = xs + ksum*ln2 + log( sum_j q_j * exp(end_j) )
        float term = q * __expf(en[lane]);
        #pragma unroll
        for (int d = 32; d > 0; d >>= 1) term += __shfl_xor(term, d);
        if (lane == 0)
            atomicAdd(out, -(xs + (float)ksum * LN2F + __logf(term)));
    } else {
        // ---------------- numerator: tag-path score (grid-stride gather) -------
        const int t0 = (blockIdx.x - BATCH) * 64 + lane;
        float acc = 0.f;
        for (int idx = t0; idx < SEQ * BATCH; idx += NUMER_BLOCKS * 64) {
            int b = idx & (BATCH - 1);
            int s = idx >> 10;
            int L = lens[b];
            int tg = tags[s * BATCH + b];
            float v = 0.f;
            if (s == 0) {
                v = st[tg] + em[(size_t)b * NT + tg];
            } else if (s < L) {
                int tp = tags[(s - 1) * BATCH + b];
                v = tr[tp * NT + tg] + em[(size_t)s * BT + (size_t)b * NT + tg];
            }
            if (s == L - 1) v += en[tg];
            acc += v;
        }
        #pragma unroll
        for (int d = 32; d > 0; d >>= 1) acc += __shfl_xor(acc, d);
        if (lane == 0) atomicAdd(out, acc);
    }
}

extern "C" void kernel_launch(void* const* d_in, const int* in_sizes, int n_in,
                              void* d_out, int out_size, void* d_ws, size_t ws_size,
                              hipStream_t stream)
{
    const float* emissions = (const float*)d_in[0];
    const int*   tags      = (const int*)d_in[1];
    const int*   lengths   = (const int*)d_in[2];
    const float* start_tr  = (const float*)d_in[3];
    const float* end_tr    = (const float*)d_in[4];
    const float* trans     = (const float*)d_in[5];
    float* out = (float*)d_out;

    hipMemsetAsync(out, 0, sizeof(float), stream);

    crf_fused<<<BATCH + NUMER_BLOCKS, 64, 0, stream>>>(
        emissions, tags, lengths, start_tr, end_tr, trans, out);
}

// Round 4
// 237.085 us; speedup vs baseline: 1.1843x; 1.1843x over previous
//
#include <hip/hip_runtime.h>

#define SEQ 512
#define BATCH 1024
#define NT 64
#define BT (BATCH * NT)        // stride between timesteps in emissions
#define CHUNK 32               // steps per LDS-staged emission chunk
#define NUMER_BLOCKS 512
#define LN2F 0.69314718055994531f

// Fused kernel: blocks [0, BATCH) run the forward-algorithm denominator (one
// wave per chain, linear domain, power-of-2 rescaling). Emissions are staged
// global->LDS in 32-step chunks with 1-chunk-ahead prefetch so the only vmcnt
// wait is one drain per 32 steps (issued ~13k cycles after the loads).
// Blocks [BATCH, ...) accumulate the tag-path numerator.
__global__ __launch_bounds__(64, 1) void crf_fused(
    const float* __restrict__ em, const int* __restrict__ tags,
    const int* __restrict__ lens, const float* __restrict__ st,
    const float* __restrict__ en, const float* __restrict__ tr,
    float* __restrict__ out)
{
    __shared__ __align__(16) float p_sh[NT];
    __shared__ __align__(16) float em_buf[2][CHUNK][NT];
    const int lane = threadIdx.x;   // block = 1 wave

    if (blockIdx.x < BATCH) {
        // ---------------- denominator: one wave per batch chain ----------------
        const int b = blockIdx.x;
        const int L = lens[b];

        // E column: e[i] = exp(trans[i][lane])  (consumed before any chunk waits)
        float e[NT];
        #pragma unroll
        for (int i = 0; i < NT; ++i) e[i] = __expf(tr[i * NT + lane]);

        const float* emb0 = em + (size_t)b * NT;

        // init: x0_j = st_j + em0_j ; q_j = exp(x0_j - x0_0)
        float x0 = st[lane] + emb0[lane];
        float xs = __uint_as_float(
            (unsigned)__builtin_amdgcn_readfirstlane((int)__float_as_uint(x0)));
        float q = __expf(x0 - xs);
        int ksum = 0;

        // per-lane global source pattern for chunk copies:
        // issue k covers steps s0+4k..s0+4k+3; lane l -> step s0+4k+(l>>4),
        // floats (l&15)*4 .. +3 ; LDS dest is linear base + lane*16.
        const int sub_s = lane >> 4;
        const int sub_f = (lane & 15) * 4;

        const int nch = (L + CHUNK - 1) / CHUNK;

        // prologue: issue chunk 0
        {
            #pragma unroll
            for (int k = 0; k < 8; ++k) {
                const float* g = emb0 + (size_t)(4 * k + sub_s) * BT + sub_f;
                __builtin_amdgcn_global_load_lds(
                    (const __attribute__((address_space(1))) void*)g,
                    (__attribute__((address_space(3))) void*)&em_buf[0][4 * k][0],
                    16, 0, 0);
            }
        }

        int s = 1;
        for (int c = 0; c < nch; ++c) {
            // chunk c's loads were issued >=32 steps (or at prologue) ago
            asm volatile("s_waitcnt vmcnt(0)" ::: "memory");
            if (c + 1 < nch) {
                int s0 = (c + 1) * CHUNK;
                float* dst = &em_buf[(c + 1) & 1][0][0];
                #pragma unroll
                for (int k = 0; k < 8; ++k) {
                    const float* g = emb0 + (size_t)(s0 + 4 * k + sub_s) * BT + sub_f;
                    __builtin_amdgcn_global_load_lds(
                        (const __attribute__((address_space(1))) void*)g,
                        (__attribute__((address_space(3))) void*)(dst + 4 * k * NT),
                        16, 0, 0);
                }
            }
            const float* ebuf = &em_buf[c & 1][0][0];
            int send = (L < (c + 1) * CHUNK) ? L : (c + 1) * CHUNK;
            for (; s < send; ++s) {
                float emv = ebuf[(s & (CHUNK - 1)) * NT + lane];  // ds_read_b32
                p_sh[lane] = q;                                   // broadcast my prob
                float mult = __expf(emv);                         // off critical path

                float d0 = 0.f, d1 = 0.f, d2 = 0.f, d3 = 0.f;
                float d4 = 0.f, d5 = 0.f, d6 = 0.f, d7 = 0.f;
                const float4* pv = reinterpret_cast<const float4*>(p_sh);
                #pragma unroll
                for (int i = 0; i < NT; i += 8) {
                    float4 a = pv[i / 4];          // same-addr broadcast ds_read_b128
                    float4 cc = pv[i / 4 + 1];
                    d0 = fmaf(a.x,  e[i + 0], d0);
                    d1 = fmaf(a.y,  e[i + 1], d1);
                    d2 = fmaf(a.z,  e[i + 2], d2);
                    d3 = fmaf(a.w,  e[i + 3], d3);
                    d4 = fmaf(cc.x, e[i + 4], d4);
                    d5 = fmaf(cc.y, e[i + 5], d5);
                    d6 = fmaf(cc.z, e[i + 6], d6);
                    d7 = fmaf(cc.w, e[i + 7], d7);
                }
                float dot = ((d0 + d1) + (d2 + d3)) + ((d4 + d5) + (d6 + d7));
                float pj = dot * mult;             // overlaps SALU k-extraction

                unsigned b0 = (unsigned)__builtin_amdgcn_readfirstlane(
                    (int)__float_as_uint(pj));
                int k = (int)(b0 >> 23) - 127;     // pj > 0 always
                ksum += k;
                float scale = __uint_as_float((unsigned)(127 - k) << 23);  // 2^-k
                q = pj * scale;
            }
        }

        // denom_b = xs + ksum*ln2 + log( sum_j q_j * exp(end_j) )
        float term = q * __expf(en[lane]);
        #pragma unroll
        for (int d = 32; d > 0; d >>= 1) term += __shfl_xor(term, d);
        if (lane == 0)
            atomicAdd(out, -(xs + (float)ksum * LN2F + __logf(term)));
    } else {
        // ---------------- numerator: tag-path score (grid-stride gather) -------
        const int t0 = (blockIdx.x - BATCH) * 64 + lane;
        float acc = 0.f;
        for (int idx = t0; idx < SEQ * BATCH; idx += NUMER_BLOCKS * 64) {
            int b = idx & (BATCH - 1);
            int s = idx >> 10;
            int L = lens[b];
            int tg = tags[s * BATCH + b];
            float v = 0.f;
            if (s == 0) {
                v = st[tg] + em[(size_t)b * NT + tg];
            } else if (s < L) {
                int tp = tags[(s - 1) * BATCH + b];
                v = tr[tp * NT + tg] + em[(size_t)s * BT + (size_t)b * NT + tg];
            }
            if (s == L - 1) v += en[tg];
            acc += v;
        }
        #pragma unroll
        for (int d = 32; d > 0; d >>= 1) acc += __shfl_xor(acc, d);
        if (lane == 0) atomicAdd(out, acc);
    }
}

extern "C" void kernel_launch(void* const* d_in, const int* in_sizes, int n_in,
                              void* d_out, int out_size, void* d_ws, size_t ws_size,
                              hipStream_t stream)
{
    const float* emissions = (const float*)d_in[0];
    const int*   tags      = (const int*)d_in[1];
    const int*   lengths   = (const int*)d_in[2];
    const float* start_tr  = (const float*)d_in[3];
    const float* end_tr    = (const float*)d_in[4];
    const float* trans     = (const float*)d_in[5];
    float* out = (float*)d_out;

    hipMemsetAsync(out, 0, sizeof(float), stream);

    crf_fused<<<BATCH + NUMER_BLOCKS, 64, 0, stream>>>(
        emissions, tags, lengths, start_tr, end_tr, trans, out);
}